// Round 2
// baseline (158.596 us; speedup 1.0000x reference)
//
#include <hip/hip_runtime.h>

// SpiralConv: out[b,t,d] = Re( phazor_init[d] * sum_{s<=t} phazor[d]^(t-s) x[b,s,d]
//                              + last_conv[b,d] * phazor[d]^(t+1) )
// == first-order complex linear recurrence g[t] = a*g[t-1] + init*x[t], g[-1]=last_conv.
// 3-pass chunked scan. CHUNK=16 -> 262144 threads in passes 1/3 (4 blocks/CU,
// 4 waves/SIMD) for latency hiding; pass 2 software-pipelined (prefetch depth 8).

#define BB 4
#define LL 4096
#define DD 1024
#define CHUNK 16
#define KK (LL / CHUNK)   // 256

__device__ __forceinline__ void phazor_of(float pr, float pi, float& ar, float& ai) {
    float mag = sqrtf(pr * pr + pi * pi);
    float s = expf(-mag) / mag;   // phazor = p/|p| * exp(-|p|)
    ar = pr * s;
    ai = pi * s;
}

// Pass 1: per (b, chunk, d-quad): local scan with zero init -> S[b,k,d] (complex)
__global__ __launch_bounds__(256, 4) void spiral_pass1(
    const float* __restrict__ x,
    const float* __restrict__ p_re, const float* __restrict__ p_im,
    const float* __restrict__ in_re, const float* __restrict__ in_im,
    float2* __restrict__ S)
{
    int tid = blockIdx.x * 256 + threadIdx.x;
    int dq = tid & (DD / 4 - 1);          // 0..255  (d quad)
    int k  = (tid >> 8) & (KK - 1);       // 0..255
    int b  = tid >> 16;                   // 0..3
    int d0 = dq * 4;

    float4 prv = *(const float4*)(p_re + d0);
    float4 piv = *(const float4*)(p_im + d0);
    float4 brv = *(const float4*)(in_re + d0);
    float4 biv = *(const float4*)(in_im + d0);
    float ar[4], ai[4];
    float br[4] = {brv.x, brv.y, brv.z, brv.w};
    float bi[4] = {biv.x, biv.y, biv.z, biv.w};
    {
        float prs[4] = {prv.x, prv.y, prv.z, prv.w};
        float pis[4] = {piv.x, piv.y, piv.z, piv.w};
#pragma unroll
        for (int q = 0; q < 4; ++q) phazor_of(prs[q], pis[q], ar[q], ai[q]);
    }

    float sr[4] = {0.f, 0.f, 0.f, 0.f};
    float si[4] = {0.f, 0.f, 0.f, 0.f};
    const float* xp = x + ((size_t)(b * LL + k * CHUNK) * DD + d0);

#pragma unroll
    for (int t0 = 0; t0 < CHUNK; t0 += 8) {
        float4 xv[8];
#pragma unroll
        for (int j = 0; j < 8; ++j)
            xv[j] = *(const float4*)(xp + (size_t)(t0 + j) * DD);
#pragma unroll
        for (int j = 0; j < 8; ++j) {
            float xs[4] = {xv[j].x, xv[j].y, xv[j].z, xv[j].w};
#pragma unroll
            for (int q = 0; q < 4; ++q) {
                float nr = fmaf(ar[q], sr[q], fmaf(-ai[q], si[q], br[q] * xs[q]));
                float ni = fmaf(ar[q], si[q], fmaf( ai[q], sr[q], bi[q] * xs[q]));
                sr[q] = nr; si[q] = ni;
            }
        }
    }

    float2* Sp = S + ((size_t)(b * KK + k) * DD + d0);
#pragma unroll
    for (int q = 0; q < 4; ++q) Sp[q] = make_float2(sr[q], si[q]);
}

// Pass 2: per (b, d): scan over chunks -> chunk initial states C0[b,k,d].
// Software-pipelined: S loads prefetched 8 iterations ahead (independent of
// the scan dependency chain).
__global__ __launch_bounds__(256) void spiral_pass2(
    const float* __restrict__ p_re, const float* __restrict__ p_im,
    const float* __restrict__ lc_re, const float* __restrict__ lc_im,
    const float2* __restrict__ S,
    float2* __restrict__ C0)
{
    int tid = blockIdx.x * 256 + threadIdx.x;
    int d = tid & (DD - 1);
    int b = tid >> 10;

    float ar, ai;
    phazor_of(p_re[d], p_im[d], ar, ai);
    // qC = a^CHUNK (CHUNK = 16 = 2^4) via repeated squaring
    float qr = ar, qi = ai;
#pragma unroll
    for (int i = 0; i < 4; ++i) {
        float nr = qr * qr - qi * qi;
        float ni = 2.f * qr * qi;
        qr = nr; qi = ni;
    }

    const float2* Sp = S  + (size_t)b * KK * DD + d;
    float2*       Cp = C0 + (size_t)b * KK * DD + d;

    float cr = lc_re[b * DD + d];
    float ci = lc_im[b * DD + d];

    float2 buf[8];
#pragma unroll
    for (int j = 0; j < 8; ++j) buf[j] = Sp[(size_t)j * DD];

    for (int k = 0; k < KK; k += 8) {
#pragma unroll
        for (int j = 0; j < 8; ++j) {
            Cp[(size_t)(k + j) * DD] = make_float2(cr, ci);
            float2 s = buf[j];
            int kn = k + j + 8;
            buf[j] = Sp[(size_t)(kn < KK ? kn : KK - 1) * DD];  // prefetch ahead
            float nr = fmaf(qr, cr, fmaf(-qi, ci, s.x));
            float ni = fmaf(qr, ci, fmaf( qi, cr, s.y));
            cr = nr; ci = ni;
        }
    }
}

// Pass 3: per (b, chunk, d-quad): replay recurrence from true init, write Re(g)
__global__ __launch_bounds__(256, 4) void spiral_pass3(
    const float* __restrict__ x,
    const float* __restrict__ p_re, const float* __restrict__ p_im,
    const float* __restrict__ in_re, const float* __restrict__ in_im,
    const float2* __restrict__ C0,
    float* __restrict__ out)
{
    int tid = blockIdx.x * 256 + threadIdx.x;
    int dq = tid & (DD / 4 - 1);
    int k  = (tid >> 8) & (KK - 1);
    int b  = tid >> 16;
    int d0 = dq * 4;

    float4 prv = *(const float4*)(p_re + d0);
    float4 piv = *(const float4*)(p_im + d0);
    float4 brv = *(const float4*)(in_re + d0);
    float4 biv = *(const float4*)(in_im + d0);
    float ar[4], ai[4];
    float br[4] = {brv.x, brv.y, brv.z, brv.w};
    float bi[4] = {biv.x, biv.y, biv.z, biv.w};
    {
        float prs[4] = {prv.x, prv.y, prv.z, prv.w};
        float pis[4] = {piv.x, piv.y, piv.z, piv.w};
#pragma unroll
        for (int q = 0; q < 4; ++q) phazor_of(prs[q], pis[q], ar[q], ai[q]);
    }

    float cr[4], ci[4];
    const float2* Cp = C0 + ((size_t)(b * KK + k) * DD + d0);
#pragma unroll
    for (int q = 0; q < 4; ++q) { float2 c = Cp[q]; cr[q] = c.x; ci[q] = c.y; }

    const size_t base = (size_t)(b * LL + k * CHUNK) * DD + d0;
    const float* xp = x + base;
    float* op = out + base;

#pragma unroll
    for (int t0 = 0; t0 < CHUNK; t0 += 8) {
        float4 xv[8];
#pragma unroll
        for (int j = 0; j < 8; ++j)
            xv[j] = *(const float4*)(xp + (size_t)(t0 + j) * DD);
#pragma unroll
        for (int j = 0; j < 8; ++j) {
            float xs[4] = {xv[j].x, xv[j].y, xv[j].z, xv[j].w};
            float os[4];
#pragma unroll
            for (int q = 0; q < 4; ++q) {
                float nr = fmaf(ar[q], cr[q], fmaf(-ai[q], ci[q], br[q] * xs[q]));
                float ni = fmaf(ar[q], ci[q], fmaf( ai[q], cr[q], bi[q] * xs[q]));
                cr[q] = nr; ci[q] = ni;
                os[q] = nr;
            }
            *(float4*)(op + (size_t)(t0 + j) * DD) = make_float4(os[0], os[1], os[2], os[3]);
        }
    }
}

extern "C" void kernel_launch(void* const* d_in, const int* in_sizes, int n_in,
                              void* d_out, int out_size, void* d_ws, size_t ws_size,
                              hipStream_t stream) {
    const float* x      = (const float*)d_in[0];
    const float* p_re   = (const float*)d_in[1];
    const float* p_im   = (const float*)d_in[2];
    const float* pin_re = (const float*)d_in[3];
    const float* pin_im = (const float*)d_in[4];
    const float* lc_re  = (const float*)d_in[5];
    const float* lc_im  = (const float*)d_in[6];
    float* out = (float*)d_out;

    float2* S  = (float2*)d_ws;                      // B*K*D complex = 8 MiB
    float2* C0 = S + (size_t)BB * KK * DD;           // B*K*D complex = 8 MiB

    const int threads13 = BB * KK * (DD / 4);        // 262144
    dim3 blk(256);
    dim3 grid13(threads13 / 256);                    // 1024 blocks
    dim3 grid2((BB * DD) / 256);                     // 16 blocks

    spiral_pass1<<<grid13, blk, 0, stream>>>(x, p_re, p_im, pin_re, pin_im, S);
    spiral_pass2<<<grid2,  blk, 0, stream>>>(p_re, p_im, lc_re, lc_im, S, C0);
    spiral_pass3<<<grid13, blk, 0, stream>>>(x, p_re, p_im, pin_re, pin_im, C0, out);
}

// Round 3
// 152.060 us; speedup vs baseline: 1.0430x; 1.0430x over previous
//
#include <hip/hip_runtime.h>

// SpiralConv: out[b,t,d] = Re( phazor_init[d] * sum_{s<=t} phazor[d]^(t-s) x[b,s,d]
//                              + last_conv[b,d] * phazor[d]^(t+1) )
// == first-order complex linear recurrence g[t] = a*g[t-1] + init*x[t], g[-1]=last_conv.
// 3-pass chunked scan. CHUNK=16 -> passes 1/3 run 1024 blocks (4 blocks/CU,
// 4 waves/SIMD). Pass 2: 64 blocks x 64 threads (64 CUs), prefetch depth 16.

#define BB 4
#define LL 4096
#define DD 1024
#define CHUNK 16
#define KK (LL / CHUNK)   // 256

__device__ __forceinline__ void phazor_of(float pr, float pi, float& ar, float& ai) {
    float mag = sqrtf(pr * pr + pi * pi);
    float s = expf(-mag) / mag;   // phazor = p/|p| * exp(-|p|)
    ar = pr * s;
    ai = pi * s;
}

// Pass 1: per (b, chunk, d-quad): local scan with zero init -> S[b,k,d] (complex)
__global__ __launch_bounds__(256, 4) void spiral_pass1(
    const float* __restrict__ x,
    const float* __restrict__ p_re, const float* __restrict__ p_im,
    const float* __restrict__ in_re, const float* __restrict__ in_im,
    float2* __restrict__ S)
{
    int tid = blockIdx.x * 256 + threadIdx.x;
    int dq = tid & (DD / 4 - 1);          // 0..255  (d quad)
    int k  = (tid >> 8) & (KK - 1);       // 0..255
    int b  = tid >> 16;                   // 0..3
    int d0 = dq * 4;

    float4 prv = *(const float4*)(p_re + d0);
    float4 piv = *(const float4*)(p_im + d0);
    float4 brv = *(const float4*)(in_re + d0);
    float4 biv = *(const float4*)(in_im + d0);
    float ar[4], ai[4];
    float br[4] = {brv.x, brv.y, brv.z, brv.w};
    float bi[4] = {biv.x, biv.y, biv.z, biv.w};
    {
        float prs[4] = {prv.x, prv.y, prv.z, prv.w};
        float pis[4] = {piv.x, piv.y, piv.z, piv.w};
#pragma unroll
        for (int q = 0; q < 4; ++q) phazor_of(prs[q], pis[q], ar[q], ai[q]);
    }

    float sr[4] = {0.f, 0.f, 0.f, 0.f};
    float si[4] = {0.f, 0.f, 0.f, 0.f};
    const float* xp = x + ((size_t)(b * LL + k * CHUNK) * DD + d0);

#pragma unroll
    for (int t0 = 0; t0 < CHUNK; t0 += 8) {
        float4 xv[8];
#pragma unroll
        for (int j = 0; j < 8; ++j)
            xv[j] = *(const float4*)(xp + (size_t)(t0 + j) * DD);
#pragma unroll
        for (int j = 0; j < 8; ++j) {
            float xs[4] = {xv[j].x, xv[j].y, xv[j].z, xv[j].w};
#pragma unroll
            for (int q = 0; q < 4; ++q) {
                float nr = fmaf(ar[q], sr[q], fmaf(-ai[q], si[q], br[q] * xs[q]));
                float ni = fmaf(ar[q], si[q], fmaf( ai[q], sr[q], bi[q] * xs[q]));
                sr[q] = nr; si[q] = ni;
            }
        }
    }

    float2* Sp = S + ((size_t)(b * KK + k) * DD + d0);
#pragma unroll
    for (int q = 0; q < 4; ++q) Sp[q] = make_float2(sr[q], si[q]);
}

// Pass 2: per (b, d): scan over chunks -> chunk initial states C0[b,k,d].
// 64 blocks x 64 threads so 64 CUs share the 16 MiB of traffic.
// Prefetch depth 16: ~8 KiB in flight per CU covers L2/HBM latency.
__global__ __launch_bounds__(64) void spiral_pass2(
    const float* __restrict__ p_re, const float* __restrict__ p_im,
    const float* __restrict__ lc_re, const float* __restrict__ lc_im,
    const float2* __restrict__ S,
    float2* __restrict__ C0)
{
    int tid = blockIdx.x * 64 + threadIdx.x;
    int d = tid & (DD - 1);
    int b = tid >> 10;

    float ar, ai;
    phazor_of(p_re[d], p_im[d], ar, ai);
    // qC = a^CHUNK (CHUNK = 16 = 2^4) via repeated squaring
    float qr = ar, qi = ai;
#pragma unroll
    for (int i = 0; i < 4; ++i) {
        float nr = qr * qr - qi * qi;
        float ni = 2.f * qr * qi;
        qr = nr; qi = ni;
    }

    const float2* Sp = S  + (size_t)b * KK * DD + d;
    float2*       Cp = C0 + (size_t)b * KK * DD + d;

    float cr = lc_re[b * DD + d];
    float ci = lc_im[b * DD + d];

    float2 buf[16];
#pragma unroll
    for (int j = 0; j < 16; ++j) buf[j] = Sp[(size_t)j * DD];

    for (int k = 0; k < KK; k += 16) {
#pragma unroll
        for (int j = 0; j < 16; ++j) {
            Cp[(size_t)(k + j) * DD] = make_float2(cr, ci);
            float2 s = buf[j];
            int kn = k + j + 16;
            buf[j] = Sp[(size_t)(kn < KK ? kn : KK - 1) * DD];  // prefetch ahead
            float nr = fmaf(qr, cr, fmaf(-qi, ci, s.x));
            float ni = fmaf(qr, ci, fmaf( qi, cr, s.y));
            cr = nr; ci = ni;
        }
    }
}

// Pass 3: per (b, chunk, d-quad): replay recurrence from true init, write Re(g)
__global__ __launch_bounds__(256, 4) void spiral_pass3(
    const float* __restrict__ x,
    const float* __restrict__ p_re, const float* __restrict__ p_im,
    const float* __restrict__ in_re, const float* __restrict__ in_im,
    const float2* __restrict__ C0,
    float* __restrict__ out)
{
    int tid = blockIdx.x * 256 + threadIdx.x;
    int dq = tid & (DD / 4 - 1);
    int k  = (tid >> 8) & (KK - 1);
    int b  = tid >> 16;
    int d0 = dq * 4;

    float4 prv = *(const float4*)(p_re + d0);
    float4 piv = *(const float4*)(p_im + d0);
    float4 brv = *(const float4*)(in_re + d0);
    float4 biv = *(const float4*)(in_im + d0);
    float ar[4], ai[4];
    float br[4] = {brv.x, brv.y, brv.z, brv.w};
    float bi[4] = {biv.x, biv.y, biv.z, biv.w};
    {
        float prs[4] = {prv.x, prv.y, prv.z, prv.w};
        float pis[4] = {piv.x, piv.y, piv.z, piv.w};
#pragma unroll
        for (int q = 0; q < 4; ++q) phazor_of(prs[q], pis[q], ar[q], ai[q]);
    }

    float cr[4], ci[4];
    const float2* Cp = C0 + ((size_t)(b * KK + k) * DD + d0);
#pragma unroll
    for (int q = 0; q < 4; ++q) { float2 c = Cp[q]; cr[q] = c.x; ci[q] = c.y; }

    const size_t base = (size_t)(b * LL + k * CHUNK) * DD + d0;
    const float* xp = x + base;
    float* op = out + base;

#pragma unroll
    for (int t0 = 0; t0 < CHUNK; t0 += 8) {
        float4 xv[8];
#pragma unroll
        for (int j = 0; j < 8; ++j)
            xv[j] = *(const float4*)(xp + (size_t)(t0 + j) * DD);
#pragma unroll
        for (int j = 0; j < 8; ++j) {
            float xs[4] = {xv[j].x, xv[j].y, xv[j].z, xv[j].w};
            float os[4];
#pragma unroll
            for (int q = 0; q < 4; ++q) {
                float nr = fmaf(ar[q], cr[q], fmaf(-ai[q], ci[q], br[q] * xs[q]));
                float ni = fmaf(ar[q], ci[q], fmaf( ai[q], cr[q], bi[q] * xs[q]));
                cr[q] = nr; ci[q] = ni;
                os[q] = nr;
            }
            *(float4*)(op + (size_t)(t0 + j) * DD) = make_float4(os[0], os[1], os[2], os[3]);
        }
    }
}

extern "C" void kernel_launch(void* const* d_in, const int* in_sizes, int n_in,
                              void* d_out, int out_size, void* d_ws, size_t ws_size,
                              hipStream_t stream) {
    const float* x      = (const float*)d_in[0];
    const float* p_re   = (const float*)d_in[1];
    const float* p_im   = (const float*)d_in[2];
    const float* pin_re = (const float*)d_in[3];
    const float* pin_im = (const float*)d_in[4];
    const float* lc_re  = (const float*)d_in[5];
    const float* lc_im  = (const float*)d_in[6];
    float* out = (float*)d_out;

    float2* S  = (float2*)d_ws;                      // B*K*D complex = 8 MiB
    float2* C0 = S + (size_t)BB * KK * DD;           // B*K*D complex = 8 MiB

    const int threads13 = BB * KK * (DD / 4);        // 262144
    dim3 blk(256);
    dim3 grid13(threads13 / 256);                    // 1024 blocks

    spiral_pass1<<<grid13, blk, 0, stream>>>(x, p_re, p_im, pin_re, pin_im, S);
    spiral_pass2<<<dim3(64), dim3(64), 0, stream>>>(p_re, p_im, lc_re, lc_im, S, C0);
    spiral_pass3<<<grid13, blk, 0, stream>>>(x, p_re, p_im, pin_re, pin_im, C0, out);
}

// Round 5
// 142.793 us; speedup vs baseline: 1.1107x; 1.0649x over previous
//
#include <hip/hip_runtime.h>

// SpiralConv: g[t] = a*g[t-1] + init*x[t], g[-1]=last_conv; out = Re(g).
//   a = p/|p| * exp(-|p|).
// 4-kernel hierarchical chunked scan (CHUNK=16, 256 chunks, 8 segments x 32):
//   p1 : per (b,chunk,d)  local scan, zero init            -> S
//   p2a: per (b,seg,d)    scan 32 chunks, zero init        -> R (rel prefix), T (totals)
//   p2b: per (b,d)        scan 8 segments from last_conv   -> segC
//   p3 : per (b,chunk,d)  C0 = R + q^rel * segC (in-register), replay -> out

#define BB 4
#define LL 4096
#define DD 1024
#define CHUNK 16
#define KK 256     // LL/CHUNK
#define SEG 32     // chunks per segment
#define NSEG 8     // KK/SEG

__device__ __forceinline__ void phazor_of(float pr, float pi, float& ar, float& ai) {
    float mag = sqrtf(pr * pr + pi * pi);
    float s = expf(-mag) / mag;   // phazor = p/|p| * exp(-|p|)
    ar = pr * s;
    ai = pi * s;
}

__device__ __forceinline__ void csq(float& r, float& i) {
    float nr = r * r - i * i;
    i = 2.f * r * i;
    r = nr;
}

// ---------------- p1: chunk-local scans ----------------
__global__ __launch_bounds__(256, 4) void spiral_p1(
    const float* __restrict__ x,
    const float* __restrict__ p_re, const float* __restrict__ p_im,
    const float* __restrict__ in_re, const float* __restrict__ in_im,
    float2* __restrict__ S)
{
    int tid = blockIdx.x * 256 + threadIdx.x;
    int dq = tid & (DD / 4 - 1);
    int k  = (tid >> 8) & (KK - 1);
    int b  = tid >> 16;
    int d0 = dq * 4;

    float4 prv = *(const float4*)(p_re + d0);
    float4 piv = *(const float4*)(p_im + d0);
    float4 brv = *(const float4*)(in_re + d0);
    float4 biv = *(const float4*)(in_im + d0);
    float ar[4], ai[4];
    float br[4] = {brv.x, brv.y, brv.z, brv.w};
    float bi[4] = {biv.x, biv.y, biv.z, biv.w};
    {
        float prs[4] = {prv.x, prv.y, prv.z, prv.w};
        float pis[4] = {piv.x, piv.y, piv.z, piv.w};
#pragma unroll
        for (int q = 0; q < 4; ++q) phazor_of(prs[q], pis[q], ar[q], ai[q]);
    }

    float sr[4] = {0.f, 0.f, 0.f, 0.f};
    float si[4] = {0.f, 0.f, 0.f, 0.f};
    const float* xp = x + ((size_t)(b * LL + k * CHUNK) * DD + d0);

#pragma unroll
    for (int t0 = 0; t0 < CHUNK; t0 += 8) {
        float4 xv[8];
#pragma unroll
        for (int j = 0; j < 8; ++j)
            xv[j] = *(const float4*)(xp + (size_t)(t0 + j) * DD);
#pragma unroll
        for (int j = 0; j < 8; ++j) {
            float xs[4] = {xv[j].x, xv[j].y, xv[j].z, xv[j].w};
#pragma unroll
            for (int q = 0; q < 4; ++q) {
                float nr = fmaf(ar[q], sr[q], fmaf(-ai[q], si[q], br[q] * xs[q]));
                float ni = fmaf(ar[q], si[q], fmaf( ai[q], sr[q], bi[q] * xs[q]));
                sr[q] = nr; si[q] = ni;
            }
        }
    }

    float2* Sp = S + ((size_t)(b * KK + k) * DD + d0);
#pragma unroll
    for (int q = 0; q < 4; ++q) Sp[q] = make_float2(sr[q], si[q]);
}

// ---------------- p2a: segment-relative scans over chunks ----------------
// 256 blocks x 128 threads = 32768 = BB*NSEG*DD threads, spread over all CUs.
__global__ __launch_bounds__(128) void spiral_p2a(
    const float* __restrict__ p_re, const float* __restrict__ p_im,
    const float2* __restrict__ S,
    float2* __restrict__ R, float2* __restrict__ T)
{
    int gt  = blockIdx.x * 128 + threadIdx.x;
    int d   = gt & (DD - 1);
    int seg = (gt >> 10) & (NSEG - 1);
    int bb  = gt >> 13;

    float qr, qi;
    phazor_of(p_re[d], p_im[d], qr, qi);
#pragma unroll
    for (int i = 0; i < 4; ++i) csq(qr, qi);      // q = a^16

    const int kk0 = seg * SEG;
    const float2* Sc = S + ((size_t)bb * KK * DD + d);
    float2*       Rc = R + ((size_t)bb * KK * DD + d);

    float2 buf[8];
#pragma unroll
    for (int j = 0; j < 8; ++j) buf[j] = Sc[(size_t)(kk0 + j) * DD];

    float cr = 0.f, ci = 0.f;
    for (int i = 0; i < SEG; i += 8) {
#pragma unroll
        for (int j = 0; j < 8; ++j) {
            Rc[(size_t)(kk0 + i + j) * DD] = make_float2(cr, ci);
            float2 s = buf[j];
            int kn = i + j + 8;
            buf[j] = Sc[(size_t)(kk0 + (kn < SEG ? kn : SEG - 1)) * DD];
            float nr = fmaf(qr, cr, fmaf(-qi, ci, s.x));
            float ni = fmaf(qr, ci, fmaf( qi, cr, s.y));
            cr = nr; ci = ni;
        }
    }
    T[((size_t)bb * NSEG + seg) * DD + d] = make_float2(cr, ci);
}

// ---------------- p2b: scan over segments from last_conv ----------------
// 32 blocks x 128 threads = 4096 = BB*DD threads.
__global__ __launch_bounds__(128) void spiral_p2b(
    const float* __restrict__ p_re, const float* __restrict__ p_im,
    const float* __restrict__ lc_re, const float* __restrict__ lc_im,
    const float2* __restrict__ T,
    float2* __restrict__ segC)
{
    int gt = blockIdx.x * 128 + threadIdx.x;
    int d  = gt & (DD - 1);
    int bb = gt >> 10;

    float qr, qi;
    phazor_of(p_re[d], p_im[d], qr, qi);
#pragma unroll
    for (int i = 0; i < 9; ++i) csq(qr, qi);      // Q = a^512

    float2 tb[NSEG];
#pragma unroll
    for (int s = 0; s < NSEG; ++s) tb[s] = T[((size_t)bb * NSEG + s) * DD + d];

    float cr = lc_re[bb * DD + d];
    float ci = lc_im[bb * DD + d];
#pragma unroll
    for (int s = 0; s < NSEG; ++s) {
        segC[((size_t)bb * NSEG + s) * DD + d] = make_float2(cr, ci);
        float nr = fmaf(qr, cr, fmaf(-qi, ci, tb[s].x));
        float ni = fmaf(qr, ci, fmaf( qi, cr, tb[s].y));
        cr = nr; ci = ni;
    }
}

// ---------------- p3: combine + replay ----------------
__global__ __launch_bounds__(256, 4) void spiral_p3(
    const float* __restrict__ x,
    const float* __restrict__ p_re, const float* __restrict__ p_im,
    const float* __restrict__ in_re, const float* __restrict__ in_im,
    const float2* __restrict__ R, const float2* __restrict__ segC,
    float* __restrict__ out)
{
    int tid = blockIdx.x * 256 + threadIdx.x;
    int dq = tid & (DD / 4 - 1);
    int k  = (tid >> 8) & (KK - 1);
    int b  = tid >> 16;
    int d0 = dq * 4;
    int rel = k & (SEG - 1);
    int seg = k >> 5;

    float4 prv = *(const float4*)(p_re + d0);
    float4 piv = *(const float4*)(p_im + d0);
    float4 brv = *(const float4*)(in_re + d0);
    float4 biv = *(const float4*)(in_im + d0);
    float ar[4], ai[4];
    float br[4] = {brv.x, brv.y, brv.z, brv.w};
    float bi[4] = {biv.x, biv.y, biv.z, biv.w};
    {
        float prs[4] = {prv.x, prv.y, prv.z, prv.w};
        float pis[4] = {piv.x, piv.y, piv.z, piv.w};
#pragma unroll
        for (int q = 0; q < 4; ++q) phazor_of(prs[q], pis[q], ar[q], ai[q]);
    }

    // C0 = R + (a^16)^rel * segC   (rel is wave-uniform: k is per-block)
    float cr[4], ci[4];
    {
        const float2* Rp = R    + ((size_t)(b * KK + k) * DD + d0);
        const float2* Gp = segC + ((size_t)(b * NSEG + seg) * DD + d0);
#pragma unroll
        for (int q = 0; q < 4; ++q) {
            float qdr = ar[q], qdi = ai[q];
#pragma unroll
            for (int i = 0; i < 4; ++i) csq(qdr, qdi);     // a^16
            float pr = 1.f, pi = 0.f;
            float bpr = qdr, bpi = qdi;
#pragma unroll
            for (int bit = 0; bit < 5; ++bit) {            // (a^16)^rel
                if ((rel >> bit) & 1) {
                    float nr = pr * bpr - pi * bpi;
                    pi = pr * bpi + pi * bpr;
                    pr = nr;
                }
                csq(bpr, bpi);
            }
            float2 r = Rp[q];
            float2 g = Gp[q];
            cr[q] = r.x + pr * g.x - pi * g.y;
            ci[q] = r.y + pr * g.y + pi * g.x;
        }
    }

    const size_t base = (size_t)(b * LL + k * CHUNK) * DD + d0;
    const float* xp = x + base;
    float* op = out + base;

#pragma unroll
    for (int t0 = 0; t0 < CHUNK; t0 += 8) {
        float4 xv[8];
#pragma unroll
        for (int j = 0; j < 8; ++j)
            xv[j] = *(const float4*)(xp + (size_t)(t0 + j) * DD);
#pragma unroll
        for (int j = 0; j < 8; ++j) {
            float xs[4] = {xv[j].x, xv[j].y, xv[j].z, xv[j].w};
            float os[4];
#pragma unroll
            for (int q = 0; q < 4; ++q) {
                float nr = fmaf(ar[q], cr[q], fmaf(-ai[q], ci[q], br[q] * xs[q]));
                float ni = fmaf(ar[q], ci[q], fmaf( ai[q], cr[q], bi[q] * xs[q]));
                cr[q] = nr; ci[q] = ni;
                os[q] = nr;
            }
            *(float4*)(op + (size_t)(t0 + j) * DD) = make_float4(os[0], os[1], os[2], os[3]);
        }
    }
}

extern "C" void kernel_launch(void* const* d_in, const int* in_sizes, int n_in,
                              void* d_out, int out_size, void* d_ws, size_t ws_size,
                              hipStream_t stream) {
    const float* x      = (const float*)d_in[0];
    const float* p_re   = (const float*)d_in[1];
    const float* p_im   = (const float*)d_in[2];
    const float* pin_re = (const float*)d_in[3];
    const float* pin_im = (const float*)d_in[4];
    const float* lc_re  = (const float*)d_in[5];
    const float* lc_im  = (const float*)d_in[6];
    float* out = (float*)d_out;

    char* ws = (char*)d_ws;
    float2* S    = (float2*)(ws);                               // 8 MiB
    float2* R    = (float2*)(ws + (size_t)8  * 1024 * 1024);    // 8 MiB
    float2* T    = (float2*)(ws + (size_t)16 * 1024 * 1024);    // 256 KiB
    float2* segC = (float2*)(ws + (size_t)16 * 1024 * 1024 + 256 * 1024);  // 256 KiB

    spiral_p1 <<<dim3(1024), dim3(256), 0, stream>>>(x, p_re, p_im, pin_re, pin_im, S);
    spiral_p2a<<<dim3(256),  dim3(128), 0, stream>>>(p_re, p_im, S, R, T);
    spiral_p2b<<<dim3(32),   dim3(128), 0, stream>>>(p_re, p_im, lc_re, lc_im, T, segC);
    spiral_p3 <<<dim3(1024), dim3(256), 0, stream>>>(x, p_re, p_im, pin_re, pin_im, R, segC, out);
}

// Round 6
// 141.315 us; speedup vs baseline: 1.1223x; 1.0105x over previous
//
#include <hip/hip_runtime.h>

// SpiralConv: g[t] = a*g[t-1] + init*x[t], g[-1]=last_conv; out = Re(g).
//   a = p/|p| * exp(-|p|).
// 3-kernel hierarchical chunked scan (CHUNK=16, 256 chunks, 8 segments x 32):
//   p1 : per (b,chunk,d)  local scan, zero init            -> S
//   p2a: per (b,seg,d)    scan 32 chunks, zero init        -> R (rel prefix), T (totals)
//   p3 : per (b,chunk,d)  segC from T+lc in-register (<=7-step scan, T is
//        L2-resident), C0 = R + q^rel * segC, replay chunk -> out

#define BB 4
#define LL 4096
#define DD 1024
#define CHUNK 16
#define KK 256     // LL/CHUNK
#define SEG 32     // chunks per segment
#define NSEG 8     // KK/SEG

__device__ __forceinline__ void phazor_of(float pr, float pi, float& ar, float& ai) {
    float mag = sqrtf(pr * pr + pi * pi);
    float s = expf(-mag) / mag;   // phazor = p/|p| * exp(-|p|)
    ar = pr * s;
    ai = pi * s;
}

__device__ __forceinline__ void csq(float& r, float& i) {
    float nr = r * r - i * i;
    i = 2.f * r * i;
    r = nr;
}

// ---------------- p1: chunk-local scans ----------------
__global__ __launch_bounds__(256, 4) void spiral_p1(
    const float* __restrict__ x,
    const float* __restrict__ p_re, const float* __restrict__ p_im,
    const float* __restrict__ in_re, const float* __restrict__ in_im,
    float2* __restrict__ S)
{
    int tid = blockIdx.x * 256 + threadIdx.x;
    int dq = tid & (DD / 4 - 1);
    int k  = (tid >> 8) & (KK - 1);
    int b  = tid >> 16;
    int d0 = dq * 4;

    float4 prv = *(const float4*)(p_re + d0);
    float4 piv = *(const float4*)(p_im + d0);
    float4 brv = *(const float4*)(in_re + d0);
    float4 biv = *(const float4*)(in_im + d0);
    float ar[4], ai[4];
    float br[4] = {brv.x, brv.y, brv.z, brv.w};
    float bi[4] = {biv.x, biv.y, biv.z, biv.w};
    {
        float prs[4] = {prv.x, prv.y, prv.z, prv.w};
        float pis[4] = {piv.x, piv.y, piv.z, piv.w};
#pragma unroll
        for (int q = 0; q < 4; ++q) phazor_of(prs[q], pis[q], ar[q], ai[q]);
    }

    float sr[4] = {0.f, 0.f, 0.f, 0.f};
    float si[4] = {0.f, 0.f, 0.f, 0.f};
    const float* xp = x + ((size_t)(b * LL + k * CHUNK) * DD + d0);

#pragma unroll
    for (int t0 = 0; t0 < CHUNK; t0 += 8) {
        float4 xv[8];
#pragma unroll
        for (int j = 0; j < 8; ++j)
            xv[j] = *(const float4*)(xp + (size_t)(t0 + j) * DD);
#pragma unroll
        for (int j = 0; j < 8; ++j) {
            float xs[4] = {xv[j].x, xv[j].y, xv[j].z, xv[j].w};
#pragma unroll
            for (int q = 0; q < 4; ++q) {
                float nr = fmaf(ar[q], sr[q], fmaf(-ai[q], si[q], br[q] * xs[q]));
                float ni = fmaf(ar[q], si[q], fmaf( ai[q], sr[q], bi[q] * xs[q]));
                sr[q] = nr; si[q] = ni;
            }
        }
    }

    // packed float4 stores (2 x 16B instead of 4 x 8B)
    float4* Sp = (float4*)(S + ((size_t)(b * KK + k) * DD + d0));
    Sp[0] = make_float4(sr[0], si[0], sr[1], si[1]);
    Sp[1] = make_float4(sr[2], si[2], sr[3], si[3]);
}

// ---------------- p2a: segment-relative scans over chunks ----------------
// 256 blocks x 128 threads = 32768 = BB*NSEG*DD threads, spread over all CUs.
__global__ __launch_bounds__(128) void spiral_p2a(
    const float* __restrict__ p_re, const float* __restrict__ p_im,
    const float2* __restrict__ S,
    float2* __restrict__ R, float2* __restrict__ T)
{
    int gt  = blockIdx.x * 128 + threadIdx.x;
    int d   = gt & (DD - 1);
    int seg = (gt >> 10) & (NSEG - 1);
    int bb  = gt >> 13;

    float qr, qi;
    phazor_of(p_re[d], p_im[d], qr, qi);
#pragma unroll
    for (int i = 0; i < 4; ++i) csq(qr, qi);      // q = a^16

    const int kk0 = seg * SEG;
    const float2* Sc = S + ((size_t)bb * KK * DD + d);
    float2*       Rc = R + ((size_t)bb * KK * DD + d);

    float2 buf[8];
#pragma unroll
    for (int j = 0; j < 8; ++j) buf[j] = Sc[(size_t)(kk0 + j) * DD];

    float cr = 0.f, ci = 0.f;
    for (int i = 0; i < SEG; i += 8) {
#pragma unroll
        for (int j = 0; j < 8; ++j) {
            Rc[(size_t)(kk0 + i + j) * DD] = make_float2(cr, ci);
            float2 s = buf[j];
            int kn = i + j + 8;
            buf[j] = Sc[(size_t)(kk0 + (kn < SEG ? kn : SEG - 1)) * DD];
            float nr = fmaf(qr, cr, fmaf(-qi, ci, s.x));
            float ni = fmaf(qr, ci, fmaf( qi, cr, s.y));
            cr = nr; ci = ni;
        }
    }
    T[((size_t)bb * NSEG + seg) * DD + d] = make_float2(cr, ci);
}

// ---------------- p3: segment init + combine + replay ----------------
__global__ __launch_bounds__(256, 4) void spiral_p3(
    const float* __restrict__ x,
    const float* __restrict__ p_re, const float* __restrict__ p_im,
    const float* __restrict__ in_re, const float* __restrict__ in_im,
    const float* __restrict__ lc_re, const float* __restrict__ lc_im,
    const float2* __restrict__ R, const float2* __restrict__ T,
    float* __restrict__ out)
{
    int tid = blockIdx.x * 256 + threadIdx.x;
    int dq = tid & (DD / 4 - 1);
    int k  = (tid >> 8) & (KK - 1);
    int b  = tid >> 16;
    int d0 = dq * 4;
    int rel = k & (SEG - 1);   // wave-uniform (k is per-block)
    int seg = k >> 5;          // wave-uniform

    float4 prv = *(const float4*)(p_re + d0);
    float4 piv = *(const float4*)(p_im + d0);
    float4 brv = *(const float4*)(in_re + d0);
    float4 biv = *(const float4*)(in_im + d0);
    float ar[4], ai[4];
    float br[4] = {brv.x, brv.y, brv.z, brv.w};
    float bi[4] = {biv.x, biv.y, biv.z, biv.w};
    {
        float prs[4] = {prv.x, prv.y, prv.z, prv.w};
        float pis[4] = {piv.x, piv.y, piv.z, piv.w};
#pragma unroll
        for (int q = 0; q < 4; ++q) phazor_of(prs[q], pis[q], ar[q], ai[q]);
    }

    // --- segment init: g = scan of T from last_conv over s<seg with Q=a^512 ---
    float gr[4], gi[4];
    {
        float4 lrv = *(const float4*)(lc_re + b * DD + d0);
        float4 liv = *(const float4*)(lc_im + b * DD + d0);
        gr[0] = lrv.x; gr[1] = lrv.y; gr[2] = lrv.z; gr[3] = lrv.w;
        gi[0] = liv.x; gi[1] = liv.y; gi[2] = liv.z; gi[3] = liv.w;
        float Qr[4], Qi[4];
#pragma unroll
        for (int q = 0; q < 4; ++q) {
            Qr[q] = ar[q]; Qi[q] = ai[q];
#pragma unroll
            for (int i = 0; i < 9; ++i) csq(Qr[q], Qi[q]);   // a^512
        }
        for (int s = 0; s < seg; ++s) {                      // <=7 iters, uniform
            const float2* Tp = T + ((size_t)(b * NSEG + s) * DD + d0);
#pragma unroll
            for (int q = 0; q < 4; ++q) {
                float2 t = Tp[q];
                float nr = fmaf(Qr[q], gr[q], fmaf(-Qi[q], gi[q], t.x));
                float ni = fmaf(Qr[q], gi[q], fmaf( Qi[q], gr[q], t.y));
                gr[q] = nr; gi[q] = ni;
            }
        }
    }

    // --- C0 = R + (a^16)^rel * g ---
    float cr[4], ci[4];
    {
        const float2* Rp = R + ((size_t)(b * KK + k) * DD + d0);
#pragma unroll
        for (int q = 0; q < 4; ++q) {
            float qdr = ar[q], qdi = ai[q];
#pragma unroll
            for (int i = 0; i < 4; ++i) csq(qdr, qdi);       // a^16
            float pr = 1.f, pi = 0.f;
            float bpr = qdr, bpi = qdi;
#pragma unroll
            for (int bit = 0; bit < 5; ++bit) {              // (a^16)^rel
                if ((rel >> bit) & 1) {
                    float nr = pr * bpr - pi * bpi;
                    pi = pr * bpi + pi * bpr;
                    pr = nr;
                }
                csq(bpr, bpi);
            }
            float2 r = Rp[q];
            cr[q] = r.x + pr * gr[q] - pi * gi[q];
            ci[q] = r.y + pr * gi[q] + pi * gr[q];
        }
    }

    const size_t base = (size_t)(b * LL + k * CHUNK) * DD + d0;
    const float* xp = x + base;
    float* op = out + base;

#pragma unroll
    for (int t0 = 0; t0 < CHUNK; t0 += 8) {
        float4 xv[8];
#pragma unroll
        for (int j = 0; j < 8; ++j)
            xv[j] = *(const float4*)(xp + (size_t)(t0 + j) * DD);
#pragma unroll
        for (int j = 0; j < 8; ++j) {
            float xs[4] = {xv[j].x, xv[j].y, xv[j].z, xv[j].w};
            float os[4];
#pragma unroll
            for (int q = 0; q < 4; ++q) {
                float nr = fmaf(ar[q], cr[q], fmaf(-ai[q], ci[q], br[q] * xs[q]));
                float ni = fmaf(ar[q], ci[q], fmaf( ai[q], cr[q], bi[q] * xs[q]));
                cr[q] = nr; ci[q] = ni;
                os[q] = nr;
            }
            *(float4*)(op + (size_t)(t0 + j) * DD) = make_float4(os[0], os[1], os[2], os[3]);
        }
    }
}

extern "C" void kernel_launch(void* const* d_in, const int* in_sizes, int n_in,
                              void* d_out, int out_size, void* d_ws, size_t ws_size,
                              hipStream_t stream) {
    const float* x      = (const float*)d_in[0];
    const float* p_re   = (const float*)d_in[1];
    const float* p_im   = (const float*)d_in[2];
    const float* pin_re = (const float*)d_in[3];
    const float* pin_im = (const float*)d_in[4];
    const float* lc_re  = (const float*)d_in[5];
    const float* lc_im  = (const float*)d_in[6];
    float* out = (float*)d_out;

    char* ws = (char*)d_ws;
    float2* S = (float2*)(ws);                              // 8 MiB
    float2* R = (float2*)(ws + (size_t)8  * 1024 * 1024);   // 8 MiB
    float2* T = (float2*)(ws + (size_t)16 * 1024 * 1024);   // 256 KiB

    spiral_p1 <<<dim3(1024), dim3(256), 0, stream>>>(x, p_re, p_im, pin_re, pin_im, S);
    spiral_p2a<<<dim3(256),  dim3(128), 0, stream>>>(p_re, p_im, S, R, T);
    spiral_p3 <<<dim3(1024), dim3(256), 0, stream>>>(x, p_re, p_im, pin_re, pin_im,
                                                     lc_re, lc_im, R, T, out);
}